// Round 19
// baseline (257.939 us; speedup 1.0000x reference)
//
#include <hip/hip_runtime.h>
#include <math.h>

#define HEADS 4
#define HID 64
#define D1 256
#define NGR 1024
#define NEG 0.2f

typedef __attribute__((ext_vector_type(8))) short bf16x8;
typedef __attribute__((ext_vector_type(4))) float f32x4;

static inline int cdiv(int a, int b) { return (a + b - 1) / b; }

__device__ inline unsigned short f2b(float f) {
    union { float f; unsigned u; } v; v.f = f;
    unsigned r = v.u + 0x7FFFu + ((v.u >> 16) & 1u);
    return (unsigned short)(r >> 16);
}
__device__ inline float b2f(unsigned short u) {
    union { unsigned u; float f; } v; v.u = ((unsigned)u) << 16;
    return v.f;
}
__device__ inline float b2f_lo(unsigned u) {
    union { unsigned u; float f; } v; v.u = u << 16; return v.f;
}
__device__ inline float b2f_hi(unsigned u) {
    union { unsigned u; float f; } v; v.u = u & 0xffff0000u; return v.f;
}

// ---------------- init: zero deg/fill/counter + Btb (W2^T + alpha ext) + va1 ----------------
__global__ void k_init(const float* __restrict__ W1, const float* __restrict__ asrc1,
                       const float* __restrict__ adst1, const float* __restrict__ W2,
                       const float* __restrict__ asrc2, const float* __restrict__ adst2,
                       unsigned short* __restrict__ Btb, float* __restrict__ va1,
                       int* __restrict__ deg, int* __restrict__ fill,
                       int* __restrict__ gcnt, int N) {
    int gt = blockIdx.x * 256 + threadIdx.x, gs = gridDim.x * 256;
    for (int i = gt; i < N; i += gs) { deg[i] = 0; fill[i] = 0; }
    for (int i = gt; i < 65536; i += gs) {
        int c = i & 255, k = i >> 8;
        Btb[c * D1 + k] = f2b(W2[k * D1 + c]);
    }
    for (int i = gt; i < 2048; i += gs) {
        int c = i >> 8, k = i & 255, h = c & 3;
        const float* avec = ((c < 4) ? asrc2 : adst2) + h * HID;
        const float* wrow = W2 + k * D1 + h * HID;
        float s = 0.f;
#pragma unroll 8
        for (int j = 0; j < HID; ++j) s += wrow[j] * avec[j];
        Btb[(256 + c) * D1 + k] = f2b(s);
    }
    for (int i = gt; i < 48; i += gs) {
        int k = i / 8, h8 = i % 8, h = h8 & 3;
        const float* avec = (h8 < 4) ? (asrc1 + h * HID) : (adst1 + h * HID);
        const float* wrow = W1 + k * D1 + h * HID;
        float s = 0.f;
#pragma unroll 8
        for (int j = 0; j < HID; ++j) s += wrow[j] * avec[j];
        va1[k * 8 + h8] = s;
    }
    if (gt == 0) *gcnt = 0;
}

// ---------------- degree histogram (XCD-dst-filtered) + layer-1 alphas + padded x ----------------
__global__ void k_dega(const int* __restrict__ ei, int E, int ET, int* __restrict__ deg,
                       const float* __restrict__ x, const float* __restrict__ va1,
                       float* __restrict__ as_, float* __restrict__ ad_,
                       float* __restrict__ xf8, int N) {
    int grp = blockIdx.x & 7;
    int gb = blockIdx.x >> 3, ng = gridDim.x >> 3;
    for (int e = gb * 256 + threadIdx.x; e < ET; e += ng * 256) {
        int d = (e < E) ? ei[E + e] : e - E;
        if (((d >> 8) & 7) == grp) atomicAdd(&deg[d], 1);
    }
    int gt = blockIdx.x * 256 + threadIdx.x, gs = gridDim.x * 256;
    for (int n = gt; n < N; n += gs) {
        float2 x01 = *(const float2*)(x + n * 6);
        float2 x23 = *(const float2*)(x + n * 6 + 2);
        float2 x45 = *(const float2*)(x + n * 6 + 4);
        float xv[6] = {x01.x, x01.y, x23.x, x23.y, x45.x, x45.y};
        ((float4*)xf8)[(unsigned)n * 2u] = make_float4(xv[0], xv[1], xv[2], xv[3]);
        ((float4*)xf8)[(unsigned)n * 2u + 1] = make_float4(xv[4], xv[5], 0.f, 0.f);
        float4 sv, dv;
#pragma unroll
        for (int h = 0; h < 4; ++h) {
            float s = 0.f, d = 0.f;
#pragma unroll
            for (int k = 0; k < 6; ++k) {
                s += xv[k] * va1[k * 8 + h];
                d += xv[k] * va1[k * 8 + 4 + h];
            }
            (&sv.x)[h] = s; (&dv.x)[h] = d;
        }
        ((float4*)as_)[n] = sv;
        ((float4*)ad_)[n] = dv;
    }
}

// ---------------- row offsets via block-atomic base ----------------
__global__ void k_off(const int* __restrict__ deg, int* __restrict__ rowp,
                      int* __restrict__ gcnt, int N) {
    __shared__ int sd[256];
    __shared__ int sbase;
    int t = threadIdx.x;
    int i = blockIdx.x * 256 + t;
    int v = (i < N) ? deg[i] : 0;
    sd[t] = v;
    __syncthreads();
    for (int off = 1; off < 256; off <<= 1) {
        int u = (t >= off) ? sd[t - off] : 0;
        __syncthreads();
        sd[t] += u;
        __syncthreads();
    }
    if (t == 255) sbase = atomicAdd(gcnt, sd[255]);
    __syncthreads();
    if (i < N) rowp[i] = sbase + sd[t] - v;
}

// ---------------- scatter (XCD-dst-filtered) ----------------
__global__ void k_scatter(const int* __restrict__ ei, int E, int ET,
                          const int* __restrict__ rowp, int* __restrict__ fill,
                          int* __restrict__ csrc) {
    int grp = blockIdx.x & 7;
    int gb = blockIdx.x >> 3, ng = gridDim.x >> 3;
    for (int e = gb * 256 + threadIdx.x; e < ET; e += ng * 256) {
        int d = (e < E) ? ei[E + e] : e - E;
        if (((d >> 8) & 7) != grp) continue;
        int s = (e < E) ? ei[e] : d;
        int pos = rowp[d] + atomicAdd(&fill[d], 1);
        csrc[pos] = s;
    }
}

// ---------------- layer-1 aggregate: one wave per dst = 4 heads x 16 slots (TB=128) ----------------
__global__ void k_aggr1(const int* __restrict__ rowp, const int* __restrict__ deg,
                        const int* __restrict__ csrc,
                        const float* __restrict__ as_, const float* __restrict__ ad_,
                        const float* __restrict__ xf8, const float* __restrict__ W1,
                        const float* __restrict__ b1, unsigned short* __restrict__ outb, int N) {
    int d = blockIdx.x * 2 + (threadIdx.x >> 6);
    if (d >= N) return;
    int l = threadIdx.x & 63;
    int h = l & 3, sl = l >> 2;
    int lo = rowp[d], hi = lo + deg[d];
    float adh = ad_[(unsigned)d * 4u + h];
    float a0 = 0.f, a1 = 0.f, a2 = 0.f, a3 = 0.f, a4 = 0.f, a5 = 0.f;
    float den = 0.f;
    const float4* xv8 = (const float4*)xf8;
    for (int k = lo + sl; k < hi; k += 16) {
        int s = csrc[k];
        float v = as_[(unsigned)s * 4u + h] + adh;
        v = v > 0.f ? v : NEG * v;
        float e = __expf(v);
        den += e;
        float4 xa = xv8[(unsigned)s * 2u];
        float4 xc = xv8[(unsigned)s * 2u + 1];
        a0 += e * xa.x; a1 += e * xa.y;
        a2 += e * xa.z; a3 += e * xa.w;
        a4 += e * xc.x; a5 += e * xc.y;
    }
#pragma unroll
    for (int off = 4; off < 64; off <<= 1) {
        den += __shfl_xor(den, off);
        a0 += __shfl_xor(a0, off); a1 += __shfl_xor(a1, off);
        a2 += __shfl_xor(a2, off); a3 += __shfl_xor(a3, off);
        a4 += __shfl_xor(a4, off); a5 += __shfl_xor(a5, off);
    }
    int src = (l & 60) | (l >> 4);
    den = __shfl(den, src);
    a0 = __shfl(a0, src); a1 = __shfl(a1, src);
    a2 = __shfl(a2, src); a3 = __shfl(a3, src);
    a4 = __shfl(a4, src); a5 = __shfl(a5, src);
    float inv = 1.f / (den + 1e-16f);
    int c0 = l * 4;
    ushort4 ub;
#pragma unroll
    for (int cc = 0; cc < 4; ++cc) {
        int c = c0 + cc;
        float o = a0 * W1[c] + a1 * W1[D1 + c] + a2 * W1[2 * D1 + c] +
                  a3 * W1[3 * D1 + c] + a4 * W1[4 * D1 + c] + a5 * W1[5 * D1 + c];
        o = o * inv + b1[c];
        o = o > 0.f ? o : (__expf(o) - 1.f);
        (&ub.x)[cc] = f2b(o);
    }
    *(ushort4*)(outb + (size_t)d * D1 + c0) = ub;
}

// ---------------- LDS-staged bf16 MFMA GEMM with coalesced epilogue ----------------
#define BPITCH 264
#define OP 72
__global__ void k_mm(const unsigned short* __restrict__ A, const unsigned short* __restrict__ Bt,
                     unsigned short* __restrict__ C, float* __restrict__ as_,
                     float* __restrict__ ad_, int N) {
    __shared__ unsigned short sb[80 * BPITCH];
    int nwg = gridDim.x;
    int bid = blockIdx.x;
    int xcd = bid & 7, off = bid >> 3;
    int qq = nwg >> 3, rr = nwg & 7;
    int lin = (xcd < rr) ? (xcd * (qq + 1) + off) : (rr * (qq + 1) + (xcd - rr) * qq + off);
    int xblk = lin >> 2, y = lin & 3;

    int t = threadIdx.x;
#pragma unroll
    for (int c = 0; c < 10; ++c) {
        int idx = c * 256 + t;
        int r = idx >> 5, ch = idx & 31;
        uint4 v = make_uint4(0, 0, 0, 0);
        int src = -1;
        if (r < 64) src = y * 64 + r;
        else if (r < 72 && y == 0) src = 256 + (r - 64);
        if (src >= 0) v = *(const uint4*)(Bt + (size_t)src * D1 + ch * 8);
        *(uint4*)(&sb[r * BPITCH + ch * 8]) = v;
    }
    __syncthreads();

    int w = t >> 6, l = t & 63;
    int lr = l & 15, lk = (l >> 4) * 8;
    int r0w = xblk * 256 + w * 64;
    const unsigned short* aptr[4];
#pragma unroll
    for (int m = 0; m < 4; ++m) {
        int ar = r0w + m * 16 + lr;
        if (ar >= N) ar = N - 1;
        aptr[m] = A + (size_t)ar * D1 + lk;
    }
    f32x4 acc[4][4];
    f32x4 accE[4];
#pragma unroll
    for (int m = 0; m < 4; ++m) {
        accE[m] = (f32x4){0.f, 0.f, 0.f, 0.f};
#pragma unroll
        for (int n = 0; n < 4; ++n) acc[m][n] = (f32x4){0.f, 0.f, 0.f, 0.f};
    }
#pragma unroll
    for (int ks = 0; ks < 8; ++ks) {
        bf16x8 av[4];
#pragma unroll
        for (int m = 0; m < 4; ++m) av[m] = *(const bf16x8*)(aptr[m] + ks * 32);
#pragma unroll
        for (int n = 0; n < 4; ++n) {
            bf16x8 bv = *(const bf16x8*)(&sb[(n * 16 + lr) * BPITCH + ks * 32 + lk]);
#pragma unroll
            for (int m = 0; m < 4; ++m)
                acc[m][n] = __builtin_amdgcn_mfma_f32_16x16x32_bf16(av[m], bv, acc[m][n], 0, 0, 0);
        }
        if (y == 0) {
            bf16x8 be = *(const bf16x8*)(&sb[(64 + lr) * BPITCH + ks * 32 + lk]);
#pragma unroll
            for (int m = 0; m < 4; ++m)
                accE[m] = __builtin_amdgcn_mfma_f32_16x16x32_bf16(av[m], be, accE[m], 0, 0, 0);
        }
    }
    int rsub = (l >> 4) * 4;
    if (y == 0) {
#pragma unroll
        for (int m = 0; m < 4; ++m) {
#pragma unroll
            for (int r = 0; r < 4; ++r) {
                int row = r0w + m * 16 + rsub + r;
                if (row < N) {
                    float v = accE[m][r];
                    if (lr < 4) as_[row * HEADS + lr] = v;
                    else if (lr < 8) ad_[row * HEADS + (lr - 4)] = v;
                }
            }
        }
    }
    __syncthreads();
#pragma unroll
    for (int m = 0; m < 4; ++m) {
        int lrow = w * 64 + m * 16 + rsub;
#pragma unroll
        for (int r = 0; r < 4; ++r) {
#pragma unroll
            for (int n = 0; n < 4; ++n)
                sb[(lrow + r) * OP + n * 16 + lr] = f2b(acc[m][n][r]);
        }
    }
    __syncthreads();
    int rbase = xblk * 256;
#pragma unroll
    for (int i = t; i < 2048; i += 256) {
        int row = i >> 3, seg = i & 7;
        int grow = rbase + row;
        if (grow < N) {
            uint4 v = *(const uint4*)&sb[row * OP + seg * 8];
            *(uint4*)(C + (size_t)grow * D1 + y * 64 + seg * 8) = v;
        }
    }
}

// ---------------- layer-2 aggregate: 32 lanes/dst, uint4 gathers, dst-range ----------------
__global__ void k_aggr2(const int* __restrict__ rowp, const int* __restrict__ deg,
                        const int* __restrict__ csrc,
                        const float* __restrict__ as_, const float* __restrict__ ad_,
                        const unsigned short* __restrict__ xb, const float* __restrict__ bias,
                        unsigned short* __restrict__ outb, int d0, int d1) {
    int d = d0 + blockIdx.x * 4 + (threadIdx.x >> 5);
    if (d >= d1) return;
    int t = threadIdx.x & 31;
    int h = t >> 3;
    int lo = rowp[d], hi = lo + deg[d];
    float adh = ad_[(unsigned)d * 4u + h];
    const uint4* xbv = (const uint4*)xb;

    float a0 = 0.f, a1 = 0.f, a2 = 0.f, a3 = 0.f;
    float a4 = 0.f, a5 = 0.f, a6 = 0.f, a7 = 0.f;
    float den = 0.f;
    int k = lo;
    for (; k + 3 < hi; k += 4) {
        int s0 = csrc[k], s1 = csrc[k + 1], s2 = csrc[k + 2], s3 = csrc[k + 3];
        float w0 = as_[(unsigned)s0 * 4u + h] + adh;
        float w1 = as_[(unsigned)s1 * 4u + h] + adh;
        float w2 = as_[(unsigned)s2 * 4u + h] + adh;
        float w3 = as_[(unsigned)s3 * 4u + h] + adh;
        uint4 u0 = xbv[(unsigned)s0 * 32u + t];
        uint4 u1 = xbv[(unsigned)s1 * 32u + t];
        uint4 u2 = xbv[(unsigned)s2 * 32u + t];
        uint4 u3 = xbv[(unsigned)s3 * 32u + t];
        w0 = w0 > 0.f ? w0 : NEG * w0;
        w1 = w1 > 0.f ? w1 : NEG * w1;
        w2 = w2 > 0.f ? w2 : NEG * w2;
        w3 = w3 > 0.f ? w3 : NEG * w3;
        float e0 = __expf(w0), e1 = __expf(w1);
        float e2 = __expf(w2), e3 = __expf(w3);
        den += e0 + e1 + e2 + e3;
        a0 += e0 * b2f_lo(u0.x) + e1 * b2f_lo(u1.x) + e2 * b2f_lo(u2.x) + e3 * b2f_lo(u3.x);
        a1 += e0 * b2f_hi(u0.x) + e1 * b2f_hi(u1.x) + e2 * b2f_hi(u2.x) + e3 * b2f_hi(u3.x);
        a2 += e0 * b2f_lo(u0.y) + e1 * b2f_lo(u1.y) + e2 * b2f_lo(u2.y) + e3 * b2f_lo(u3.y);
        a3 += e0 * b2f_hi(u0.y) + e1 * b2f_hi(u1.y) + e2 * b2f_hi(u2.y) + e3 * b2f_hi(u3.y);
        a4 += e0 * b2f_lo(u0.z) + e1 * b2f_lo(u1.z) + e2 * b2f_lo(u2.z) + e3 * b2f_lo(u3.z);
        a5 += e0 * b2f_hi(u0.z) + e1 * b2f_hi(u1.z) + e2 * b2f_hi(u2.z) + e3 * b2f_hi(u3.z);
        a6 += e0 * b2f_lo(u0.w) + e1 * b2f_lo(u1.w) + e2 * b2f_lo(u2.w) + e3 * b2f_lo(u3.w);
        a7 += e0 * b2f_hi(u0.w) + e1 * b2f_hi(u1.w) + e2 * b2f_hi(u2.w) + e3 * b2f_hi(u3.w);
    }
    for (; k < hi; ++k) {
        int s0 = csrc[k];
        float v0 = as_[(unsigned)s0 * 4u + h] + adh; v0 = v0 > 0.f ? v0 : NEG * v0;
        float e0 = __expf(v0);
        uint4 u0 = xbv[(unsigned)s0 * 32u + t];
        den += e0;
        a0 += e0 * b2f_lo(u0.x); a1 += e0 * b2f_hi(u0.x);
        a2 += e0 * b2f_lo(u0.y); a3 += e0 * b2f_hi(u0.y);
        a4 += e0 * b2f_lo(u0.z); a5 += e0 * b2f_hi(u0.z);
        a6 += e0 * b2f_lo(u0.w); a7 += e0 * b2f_hi(u0.w);
    }
    float inv = 1.f / (den + 1e-16f);
    float4 bv0 = ((const float4*)bias)[t * 2];
    float4 bv1 = ((const float4*)bias)[t * 2 + 1];
    float o[8];
    o[0] = a0 * inv + bv0.x; o[1] = a1 * inv + bv0.y;
    o[2] = a2 * inv + bv0.z; o[3] = a3 * inv + bv0.w;
    o[4] = a4 * inv + bv1.x; o[5] = a5 * inv + bv1.y;
    o[6] = a6 * inv + bv1.z; o[7] = a7 * inv + bv1.w;
    uint4 ub;
    unsigned* up = &ub.x;
#pragma unroll
    for (int i = 0; i < 4; ++i) {
        float lo_f = o[i * 2], hi_f = o[i * 2 + 1];
        lo_f = lo_f > 0.f ? lo_f : (__expf(lo_f) - 1.f);
        hi_f = hi_f > 0.f ? hi_f : (__expf(hi_f) - 1.f);
        up[i] = (unsigned)f2b(lo_f) | ((unsigned)f2b(hi_f) << 16);
    }
    ((uint4*)(outb + (size_t)d * D1))[t] = ub;
}

// ---------------- fused mean-pool + KAN: vectorized pool + 1 graph/block ----------------

__device__ inline void bspl8(float x, float* out) {
    float t[12];
#pragma unroll
    for (int j = 0; j < 12; ++j) t[j] = (j - 3) * 0.4f - 1.0f;
    float bb[11];
#pragma unroll
    for (int j = 0; j < 11; ++j) bb[j] = (x >= t[j] && x < t[j + 1]) ? 1.f : 0.f;
#pragma unroll
    for (int k = 1; k <= 3; ++k) {
#pragma unroll
        for (int j = 0; j + k < 11; ++j) {
            float dl = t[j + k] - t[j];
            float dr = t[j + k + 1] - t[j + 1];
            bb[j] = (x - t[j]) / dl * bb[j] + (t[j + k + 1] - x) / dr * bb[j + 1];
        }
    }
#pragma unroll
    for (int p = 0; p < 8; ++p) out[p] = bb[p];
}

__device__ inline float siluf(float x) { return x / (1.f + __expf(-x)); }

__global__ void k_poolkan(const unsigned short* __restrict__ hb2, const int* __restrict__ batch,
                          const float* __restrict__ bw1, const float* __restrict__ sw1,
                          const float* __restrict__ sc1, const float* __restrict__ bw2,
                          const float* __restrict__ sw2, const float* __restrict__ sc2,
                          float* __restrict__ out, int N) {
    __shared__ float sP[8][256];
    __shared__ float sB[D1][9];
    __shared__ float sS[D1];
    __shared__ float sZ[32];
    int g = blockIdx.x;
    int lo = 0, hi = N;
    while (lo < hi) { int m = (lo + hi) >> 1; if (batch[m] < g) lo = m + 1; else hi = m; }
    int lo2 = lo, hi2 = N;
    while (lo2 < hi2) { int m = (lo2 + hi2) >> 1; if (batch[m] < g + 1) lo2 = m + 1; else hi2 = m; }
    int i = threadIdx.x;
    int rg = i >> 5, cg = i & 31;
    float ps[8];
#pragma unroll
    for (int j = 0; j < 8; ++j) ps[j] = 0.f;
    const uint4* hv = (const uint4*)hb2;
    for (int n = lo + rg; n < lo2; n += 8) {
        uint4 u = hv[(size_t)n * 32 + cg];
        ps[0] += b2f_lo(u.x); ps[1] += b2f_hi(u.x);
        ps[2] += b2f_lo(u.y); ps[3] += b2f_hi(u.y);
        ps[4] += b2f_lo(u.z); ps[5] += b2f_hi(u.z);
        ps[6] += b2f_lo(u.w); ps[7] += b2f_hi(u.w);
    }
#pragma unroll
    for (int j = 0; j < 8; ++j) sP[rg][cg * 8 + j] = ps[j];
    __syncthreads();
    float xi = 0.f;
#pragma unroll
    for (int r2 = 0; r2 < 8; ++r2) xi += sP[r2][i];
    xi /= (float)max(lo2 - lo, 1);
    float b[8];
    bspl8(xi, b);
#pragma unroll
    for (int p = 0; p < 8; ++p) sB[i][p] = b[p];
    sS[i] = siluf(xi);
    __syncthreads();
    int wv = i >> 6, l = i & 63;
    for (int oo = 0; oo < 8; ++oo) {
        int o = wv * 8 + oo;
        float part = 0.f;
        for (int ii = l; ii < D1; ii += 64) {
            float sc = sc1[o * D1 + ii];
            float p0 = sS[ii] * bw1[o * D1 + ii];
            const float* sw = sw1 + ((size_t)o * D1 + ii) * 8;
#pragma unroll
            for (int p = 0; p < 8; ++p) p0 += sB[ii][p] * sw[p] * sc;
            part += p0;
        }
#pragma unroll
        for (int off = 32; off >= 1; off >>= 1) part += __shfl_down(part, off);
        if (l == 0) sZ[o] = part;
    }
    __syncthreads();
    if (i < 64) {
        float part = 0.f;
        if (i < 32) {
            float z = sZ[i];
            float b2a[8];
            bspl8(z, b2a);
            part = siluf(z) * bw2[i];
            float sc = sc2[i];
#pragma unroll
            for (int p = 0; p < 8; ++p) part += b2a[p] * sw2[i * 8 + p] * sc;
        }
#pragma unroll
        for (int off = 32; off >= 1; off >>= 1) part += __shfl_down(part, off);
        if (i == 0) out[g] = part;
    }
}

extern "C" void kernel_launch(void* const* d_in, const int* in_sizes, int n_in,
                              void* d_out, int out_size, void* d_ws, size_t ws_size,
                              hipStream_t stream) {
    const float* x      = (const float*)d_in[0];
    const int*   ei     = (const int*)d_in[1];
    const int*   batch  = (const int*)d_in[2];
    const float* W1     = (const float*)d_in[3];
    const float* asrc1  = (const float*)d_in[4];
    const float* adst1  = (const float*)d_in[5];
    const float* b1     = (const float*)d_in[6];
    const float* W2     = (const float*)d_in[7];
    const float* asrc2  = (const float*)d_in[8];
    const float* adst2  = (const float*)d_in[9];
    const float* b2     = (const float*)d_in[10];
    const float* bw1    = (const float*)d_in[11];
    const float* sw1    = (const float*)d_in[12];
    const float* sc1    = (const float*)d_in[13];
    const float* bw2    = (const float*)d_in[14];
    const float* sw2    = (const float*)d_in[15];
    const float* sc2    = (const float*)d_in[16];
    float* outp = (float*)d_out;

    const int N  = in_sizes[0] / 6;
    const int E  = in_sizes[1] / 2;
    const int ET = E + N;

    char* base = (char*)d_ws;
    unsigned short* hb  = (unsigned short*)base; base += (size_t)N * D1 * 2;
    unsigned short* xb  = (unsigned short*)base; base += (size_t)N * D1 * 2;
    unsigned short* hb2 = (unsigned short*)base; base += (size_t)N * D1 * 2;
    float* as_ = (float*)base;                   base += (size_t)N * HEADS * 4;
    float* ad_ = (float*)base;                   base += (size_t)N * HEADS * 4;
    float* xf8 = (float*)base;                   base += (size_t)N * 8 * 4;
    unsigned short* Btb = (unsigned short*)base; base += (size_t)264 * D1 * 2;
    float* va1 = (float*)base;                   base += 48 * 4;
    int* deg  = (int*)base;                      base += (size_t)N * 4;
    int* fill = (int*)base;                      base += (size_t)N * 4;
    int* rowp = (int*)base;                      base += (size_t)(N + 1) * 4;
    int* gcnt = (int*)base;                      base += 4;
    int* csrc = (int*)base;                      base += (size_t)ET * 4;

    const int TB = 256;
    int gN  = cdiv(N, TB);
    const int gXF = 2048;
    int half = (N + 1) / 2;

    k_init<<<gN, TB, 0, stream>>>(W1, asrc1, adst1, W2, asrc2, adst2, Btb, va1, deg, fill, gcnt, N);
    k_dega<<<gXF, TB, 0, stream>>>(ei, E, ET, deg, x, va1, as_, ad_, xf8, N);
    k_off<<<gN, TB, 0, stream>>>(deg, rowp, gcnt, N);
    k_scatter<<<gXF, TB, 0, stream>>>(ei, E, ET, rowp, fill, csrc);
    k_aggr1<<<cdiv(N, 2), 128, 0, stream>>>(rowp, deg, csrc, as_, ad_, xf8, W1, b1, hb, N);
    k_mm<<<cdiv(N, 256) * 4, TB, 0, stream>>>(hb, Btb, xb, as_, ad_, N);
    k_aggr2<<<cdiv(half, 4), 128, 0, stream>>>(rowp, deg, csrc, as_, ad_, xb, b2, hb2, 0, half);
    k_aggr2<<<cdiv(N - half, 4), 128, 0, stream>>>(rowp, deg, csrc, as_, ad_, xb, b2, hb2, half, N);
    k_poolkan<<<NGR, TB, 0, stream>>>(hb2, batch, bw1, sw1, sc1, bw2, sw2, sc2, outp, N);
}

// Round 20
// 251.231 us; speedup vs baseline: 1.0267x; 1.0267x over previous
//
#include <hip/hip_runtime.h>
#include <math.h>

#define HEADS 4
#define HID 64
#define D1 256
#define NGR 1024
#define NEG 0.2f

typedef __attribute__((ext_vector_type(8))) short bf16x8;
typedef __attribute__((ext_vector_type(4))) float f32x4;

static inline int cdiv(int a, int b) { return (a + b - 1) / b; }

__device__ inline unsigned short f2b(float f) {
    union { float f; unsigned u; } v; v.f = f;
    unsigned r = v.u + 0x7FFFu + ((v.u >> 16) & 1u);
    return (unsigned short)(r >> 16);
}
__device__ inline float b2f(unsigned short u) {
    union { unsigned u; float f; } v; v.u = ((unsigned)u) << 16;
    return v.f;
}
__device__ inline float b2f_lo(unsigned u) {
    union { unsigned u; float f; } v; v.u = u << 16; return v.f;
}
__device__ inline float b2f_hi(unsigned u) {
    union { unsigned u; float f; } v; v.u = u & 0xffff0000u; return v.f;
}

// ---------------- init: zero deg/fill/counter + Btb (W2^T + alpha ext) + va1 ----------------
__global__ void k_init(const float* __restrict__ W1, const float* __restrict__ asrc1,
                       const float* __restrict__ adst1, const float* __restrict__ W2,
                       const float* __restrict__ asrc2, const float* __restrict__ adst2,
                       unsigned short* __restrict__ Btb, float* __restrict__ va1,
                       int* __restrict__ deg, int* __restrict__ fill,
                       int* __restrict__ gcnt, int N) {
    int gt = blockIdx.x * 256 + threadIdx.x, gs = gridDim.x * 256;
    for (int i = gt; i < N; i += gs) { deg[i] = 0; fill[i] = 0; }
    for (int i = gt; i < 65536; i += gs) {
        int c = i & 255, k = i >> 8;
        Btb[c * D1 + k] = f2b(W2[k * D1 + c]);
    }
    for (int i = gt; i < 2048; i += gs) {
        int c = i >> 8, k = i & 255, h = c & 3;
        const float* avec = ((c < 4) ? asrc2 : adst2) + h * HID;
        const float* wrow = W2 + k * D1 + h * HID;
        float s = 0.f;
#pragma unroll 8
        for (int j = 0; j < HID; ++j) s += wrow[j] * avec[j];
        Btb[(256 + c) * D1 + k] = f2b(s);
    }
    for (int i = gt; i < 48; i += gs) {
        int k = i / 8, h8 = i % 8, h = h8 & 3;
        const float* avec = (h8 < 4) ? (asrc1 + h * HID) : (adst1 + h * HID);
        const float* wrow = W1 + k * D1 + h * HID;
        float s = 0.f;
#pragma unroll 8
        for (int j = 0; j < HID; ++j) s += wrow[j] * avec[j];
        va1[k * 8 + h8] = s;
    }
    if (gt == 0) *gcnt = 0;
}

// ---------------- degree histogram (XCD-dst-filtered) + layer-1 alphas + padded x ----------------
__global__ void k_dega(const int* __restrict__ ei, int E, int ET, int* __restrict__ deg,
                       const float* __restrict__ x, const float* __restrict__ va1,
                       float* __restrict__ as_, float* __restrict__ ad_,
                       float* __restrict__ xf8, int N) {
    int grp = blockIdx.x & 7;
    int gb = blockIdx.x >> 3, ng = gridDim.x >> 3;
    for (int e = gb * 256 + threadIdx.x; e < ET; e += ng * 256) {
        int d = (e < E) ? ei[E + e] : e - E;
        if (((d >> 8) & 7) == grp) atomicAdd(&deg[d], 1);
    }
    int gt = blockIdx.x * 256 + threadIdx.x, gs = gridDim.x * 256;
    for (int n = gt; n < N; n += gs) {
        float2 x01 = *(const float2*)(x + n * 6);
        float2 x23 = *(const float2*)(x + n * 6 + 2);
        float2 x45 = *(const float2*)(x + n * 6 + 4);
        float xv[6] = {x01.x, x01.y, x23.x, x23.y, x45.x, x45.y};
        ((float4*)xf8)[(unsigned)n * 2u] = make_float4(xv[0], xv[1], xv[2], xv[3]);
        ((float4*)xf8)[(unsigned)n * 2u + 1] = make_float4(xv[4], xv[5], 0.f, 0.f);
        float4 sv, dv;
#pragma unroll
        for (int h = 0; h < 4; ++h) {
            float s = 0.f, d = 0.f;
#pragma unroll
            for (int k = 0; k < 6; ++k) {
                s += xv[k] * va1[k * 8 + h];
                d += xv[k] * va1[k * 8 + 4 + h];
            }
            (&sv.x)[h] = s; (&dv.x)[h] = d;
        }
        ((float4*)as_)[n] = sv;
        ((float4*)ad_)[n] = dv;
    }
}

// ---------------- row offsets via block-atomic base ----------------
__global__ void k_off(const int* __restrict__ deg, int* __restrict__ rowp,
                      int* __restrict__ gcnt, int N) {
    __shared__ int sd[256];
    __shared__ int sbase;
    int t = threadIdx.x;
    int i = blockIdx.x * 256 + t;
    int v = (i < N) ? deg[i] : 0;
    sd[t] = v;
    __syncthreads();
    for (int off = 1; off < 256; off <<= 1) {
        int u = (t >= off) ? sd[t - off] : 0;
        __syncthreads();
        sd[t] += u;
        __syncthreads();
    }
    if (t == 255) sbase = atomicAdd(gcnt, sd[255]);
    __syncthreads();
    if (i < N) rowp[i] = sbase + sd[t] - v;
}

// ---------------- scatter (XCD-dst-filtered) ----------------
__global__ void k_scatter(const int* __restrict__ ei, int E, int ET,
                          const int* __restrict__ rowp, int* __restrict__ fill,
                          int* __restrict__ csrc) {
    int grp = blockIdx.x & 7;
    int gb = blockIdx.x >> 3, ng = gridDim.x >> 3;
    for (int e = gb * 256 + threadIdx.x; e < ET; e += ng * 256) {
        int d = (e < E) ? ei[E + e] : e - E;
        if (((d >> 8) & 7) != grp) continue;
        int s = (e < E) ? ei[e] : d;
        int pos = rowp[d] + atomicAdd(&fill[d], 1);
        csrc[pos] = s;
    }
}

// ---------------- layer-1 aggregate: one wave per dst = 4 heads x 16 slots (TB=128) ----------------
__global__ void k_aggr1(const int* __restrict__ rowp, const int* __restrict__ deg,
                        const int* __restrict__ csrc,
                        const float* __restrict__ as_, const float* __restrict__ ad_,
                        const float* __restrict__ xf8, const float* __restrict__ W1,
                        const float* __restrict__ b1, unsigned short* __restrict__ outb, int N) {
    int d = blockIdx.x * 2 + (threadIdx.x >> 6);
    if (d >= N) return;
    int l = threadIdx.x & 63;
    int h = l & 3, sl = l >> 2;
    int lo = rowp[d], hi = lo + deg[d];
    float adh = ad_[(unsigned)d * 4u + h];
    float a0 = 0.f, a1 = 0.f, a2 = 0.f, a3 = 0.f, a4 = 0.f, a5 = 0.f;
    float den = 0.f;
    const float4* xv8 = (const float4*)xf8;
    for (int k = lo + sl; k < hi; k += 16) {
        int s = csrc[k];
        float v = as_[(unsigned)s * 4u + h] + adh;
        v = v > 0.f ? v : NEG * v;
        float e = __expf(v);
        den += e;
        float4 xa = xv8[(unsigned)s * 2u];
        float4 xc = xv8[(unsigned)s * 2u + 1];
        a0 += e * xa.x; a1 += e * xa.y;
        a2 += e * xa.z; a3 += e * xa.w;
        a4 += e * xc.x; a5 += e * xc.y;
    }
#pragma unroll
    for (int off = 4; off < 64; off <<= 1) {
        den += __shfl_xor(den, off);
        a0 += __shfl_xor(a0, off); a1 += __shfl_xor(a1, off);
        a2 += __shfl_xor(a2, off); a3 += __shfl_xor(a3, off);
        a4 += __shfl_xor(a4, off); a5 += __shfl_xor(a5, off);
    }
    int src = (l & 60) | (l >> 4);
    den = __shfl(den, src);
    a0 = __shfl(a0, src); a1 = __shfl(a1, src);
    a2 = __shfl(a2, src); a3 = __shfl(a3, src);
    a4 = __shfl(a4, src); a5 = __shfl(a5, src);
    float inv = 1.f / (den + 1e-16f);
    int c0 = l * 4;
    ushort4 ub;
#pragma unroll
    for (int cc = 0; cc < 4; ++cc) {
        int c = c0 + cc;
        float o = a0 * W1[c] + a1 * W1[D1 + c] + a2 * W1[2 * D1 + c] +
                  a3 * W1[3 * D1 + c] + a4 * W1[4 * D1 + c] + a5 * W1[5 * D1 + c];
        o = o * inv + b1[c];
        o = o > 0.f ? o : (__expf(o) - 1.f);
        (&ub.x)[cc] = f2b(o);
    }
    *(ushort4*)(outb + (size_t)d * D1 + c0) = ub;
}

// ---------------- LDS-staged bf16 MFMA GEMM with coalesced epilogue ----------------
#define BPITCH 264
#define OP 72
__global__ void k_mm(const unsigned short* __restrict__ A, const unsigned short* __restrict__ Bt,
                     unsigned short* __restrict__ C, float* __restrict__ as_,
                     float* __restrict__ ad_, int N) {
    __shared__ unsigned short sb[80 * BPITCH];
    int nwg = gridDim.x;
    int bid = blockIdx.x;
    int xcd = bid & 7, off = bid >> 3;
    int qq = nwg >> 3, rr = nwg & 7;
    int lin = (xcd < rr) ? (xcd * (qq + 1) + off) : (rr * (qq + 1) + (xcd - rr) * qq + off);
    int xblk = lin >> 2, y = lin & 3;

    int t = threadIdx.x;
#pragma unroll
    for (int c = 0; c < 10; ++c) {
        int idx = c * 256 + t;
        int r = idx >> 5, ch = idx & 31;
        uint4 v = make_uint4(0, 0, 0, 0);
        int src = -1;
        if (r < 64) src = y * 64 + r;
        else if (r < 72 && y == 0) src = 256 + (r - 64);
        if (src >= 0) v = *(const uint4*)(Bt + (size_t)src * D1 + ch * 8);
        *(uint4*)(&sb[r * BPITCH + ch * 8]) = v;
    }
    __syncthreads();

    int w = t >> 6, l = t & 63;
    int lr = l & 15, lk = (l >> 4) * 8;
    int r0w = xblk * 256 + w * 64;
    const unsigned short* aptr[4];
#pragma unroll
    for (int m = 0; m < 4; ++m) {
        int ar = r0w + m * 16 + lr;
        if (ar >= N) ar = N - 1;
        aptr[m] = A + (size_t)ar * D1 + lk;
    }
    f32x4 acc[4][4];
    f32x4 accE[4];
#pragma unroll
    for (int m = 0; m < 4; ++m) {
        accE[m] = (f32x4){0.f, 0.f, 0.f, 0.f};
#pragma unroll
        for (int n = 0; n < 4; ++n) acc[m][n] = (f32x4){0.f, 0.f, 0.f, 0.f};
    }
#pragma unroll
    for (int ks = 0; ks < 8; ++ks) {
        bf16x8 av[4];
#pragma unroll
        for (int m = 0; m < 4; ++m) av[m] = *(const bf16x8*)(aptr[m] + ks * 32);
#pragma unroll
        for (int n = 0; n < 4; ++n) {
            bf16x8 bv = *(const bf16x8*)(&sb[(n * 16 + lr) * BPITCH + ks * 32 + lk]);
#pragma unroll
            for (int m = 0; m < 4; ++m)
                acc[m][n] = __builtin_amdgcn_mfma_f32_16x16x32_bf16(av[m], bv, acc[m][n], 0, 0, 0);
        }
        if (y == 0) {
            bf16x8 be = *(const bf16x8*)(&sb[(64 + lr) * BPITCH + ks * 32 + lk]);
#pragma unroll
            for (int m = 0; m < 4; ++m)
                accE[m] = __builtin_amdgcn_mfma_f32_16x16x32_bf16(av[m], be, accE[m], 0, 0, 0);
        }
    }
    int rsub = (l >> 4) * 4;
    if (y == 0) {
#pragma unroll
        for (int m = 0; m < 4; ++m) {
#pragma unroll
            for (int r = 0; r < 4; ++r) {
                int row = r0w + m * 16 + rsub + r;
                if (row < N) {
                    float v = accE[m][r];
                    if (lr < 4) as_[row * HEADS + lr] = v;
                    else if (lr < 8) ad_[row * HEADS + (lr - 4)] = v;
                }
            }
        }
    }
    __syncthreads();
#pragma unroll
    for (int m = 0; m < 4; ++m) {
        int lrow = w * 64 + m * 16 + rsub;
#pragma unroll
        for (int r = 0; r < 4; ++r) {
#pragma unroll
            for (int n = 0; n < 4; ++n)
                sb[(lrow + r) * OP + n * 16 + lr] = f2b(acc[m][n][r]);
        }
    }
    __syncthreads();
    int rbase = xblk * 256;
#pragma unroll
    for (int i = t; i < 2048; i += 256) {
        int row = i >> 3, seg = i & 7;
        int grow = rbase + row;
        if (grow < N) {
            uint4 v = *(const uint4*)&sb[row * OP + seg * 8];
            *(uint4*)(C + (size_t)grow * D1 + y * 64 + seg * 8) = v;
        }
    }
}

// ---------------- layer-2 aggregate: 32 lanes/dst, uint4 gathers, 4-edge pipeline ----------------
__global__ void k_aggr2(const int* __restrict__ rowp, const int* __restrict__ deg,
                        const int* __restrict__ csrc,
                        const float* __restrict__ as_, const float* __restrict__ ad_,
                        const unsigned short* __restrict__ xb, const float* __restrict__ bias,
                        unsigned short* __restrict__ outb, int N) {
    int d = blockIdx.x * 4 + (threadIdx.x >> 5);
    if (d >= N) return;
    int t = threadIdx.x & 31;
    int h = t >> 3;
    int lo = rowp[d], hi = lo + deg[d];
    float adh = ad_[(unsigned)d * 4u + h];
    const uint4* xbv = (const uint4*)xb;

    float a0 = 0.f, a1 = 0.f, a2 = 0.f, a3 = 0.f;
    float a4 = 0.f, a5 = 0.f, a6 = 0.f, a7 = 0.f;
    float den = 0.f;
    int k = lo;
    for (; k + 3 < hi; k += 4) {
        int s0 = csrc[k], s1 = csrc[k + 1], s2 = csrc[k + 2], s3 = csrc[k + 3];
        float w0 = as_[(unsigned)s0 * 4u + h] + adh;
        float w1 = as_[(unsigned)s1 * 4u + h] + adh;
        float w2 = as_[(unsigned)s2 * 4u + h] + adh;
        float w3 = as_[(unsigned)s3 * 4u + h] + adh;
        uint4 u0 = xbv[(unsigned)s0 * 32u + t];
        uint4 u1 = xbv[(unsigned)s1 * 32u + t];
        uint4 u2 = xbv[(unsigned)s2 * 32u + t];
        uint4 u3 = xbv[(unsigned)s3 * 32u + t];
        w0 = w0 > 0.f ? w0 : NEG * w0;
        w1 = w1 > 0.f ? w1 : NEG * w1;
        w2 = w2 > 0.f ? w2 : NEG * w2;
        w3 = w3 > 0.f ? w3 : NEG * w3;
        float e0 = __expf(w0), e1 = __expf(w1);
        float e2 = __expf(w2), e3 = __expf(w3);
        den += e0 + e1 + e2 + e3;
        a0 += e0 * b2f_lo(u0.x) + e1 * b2f_lo(u1.x) + e2 * b2f_lo(u2.x) + e3 * b2f_lo(u3.x);
        a1 += e0 * b2f_hi(u0.x) + e1 * b2f_hi(u1.x) + e2 * b2f_hi(u2.x) + e3 * b2f_hi(u3.x);
        a2 += e0 * b2f_lo(u0.y) + e1 * b2f_lo(u1.y) + e2 * b2f_lo(u2.y) + e3 * b2f_lo(u3.y);
        a3 += e0 * b2f_hi(u0.y) + e1 * b2f_hi(u1.y) + e2 * b2f_hi(u2.y) + e3 * b2f_hi(u3.y);
        a4 += e0 * b2f_lo(u0.z) + e1 * b2f_lo(u1.z) + e2 * b2f_lo(u2.z) + e3 * b2f_lo(u3.z);
        a5 += e0 * b2f_hi(u0.z) + e1 * b2f_hi(u1.z) + e2 * b2f_hi(u2.z) + e3 * b2f_hi(u3.z);
        a6 += e0 * b2f_lo(u0.w) + e1 * b2f_lo(u1.w) + e2 * b2f_lo(u2.w) + e3 * b2f_lo(u3.w);
        a7 += e0 * b2f_hi(u0.w) + e1 * b2f_hi(u1.w) + e2 * b2f_hi(u2.w) + e3 * b2f_hi(u3.w);
    }
    for (; k < hi; ++k) {
        int s0 = csrc[k];
        float v0 = as_[(unsigned)s0 * 4u + h] + adh; v0 = v0 > 0.f ? v0 : NEG * v0;
        float e0 = __expf(v0);
        uint4 u0 = xbv[(unsigned)s0 * 32u + t];
        den += e0;
        a0 += e0 * b2f_lo(u0.x); a1 += e0 * b2f_hi(u0.x);
        a2 += e0 * b2f_lo(u0.y); a3 += e0 * b2f_hi(u0.y);
        a4 += e0 * b2f_lo(u0.z); a5 += e0 * b2f_hi(u0.z);
        a6 += e0 * b2f_lo(u0.w); a7 += e0 * b2f_hi(u0.w);
    }
    float inv = 1.f / (den + 1e-16f);
    float4 bv0 = ((const float4*)bias)[t * 2];
    float4 bv1 = ((const float4*)bias)[t * 2 + 1];
    float o[8];
    o[0] = a0 * inv + bv0.x; o[1] = a1 * inv + bv0.y;
    o[2] = a2 * inv + bv0.z; o[3] = a3 * inv + bv0.w;
    o[4] = a4 * inv + bv1.x; o[5] = a5 * inv + bv1.y;
    o[6] = a6 * inv + bv1.z; o[7] = a7 * inv + bv1.w;
    uint4 ub;
    unsigned* up = &ub.x;
#pragma unroll
    for (int i = 0; i < 4; ++i) {
        float lo_f = o[i * 2], hi_f = o[i * 2 + 1];
        lo_f = lo_f > 0.f ? lo_f : (__expf(lo_f) - 1.f);
        hi_f = hi_f > 0.f ? hi_f : (__expf(hi_f) - 1.f);
        up[i] = (unsigned)f2b(lo_f) | ((unsigned)f2b(hi_f) << 16);
    }
    ((uint4*)(outb + (size_t)d * D1))[t] = ub;
}

// ---------------- fused mean-pool + KAN: vectorized pool + 1 graph/block ----------------

__device__ inline void bspl8(float x, float* out) {
    float t[12];
#pragma unroll
    for (int j = 0; j < 12; ++j) t[j] = (j - 3) * 0.4f - 1.0f;
    float bb[11];
#pragma unroll
    for (int j = 0; j < 11; ++j) bb[j] = (x >= t[j] && x < t[j + 1]) ? 1.f : 0.f;
#pragma unroll
    for (int k = 1; k <= 3; ++k) {
#pragma unroll
        for (int j = 0; j + k < 11; ++j) {
            float dl = t[j + k] - t[j];
            float dr = t[j + k + 1] - t[j + 1];
            bb[j] = (x - t[j]) / dl * bb[j] + (t[j + k + 1] - x) / dr * bb[j + 1];
        }
    }
#pragma unroll
    for (int p = 0; p < 8; ++p) out[p] = bb[p];
}

__device__ inline float siluf(float x) { return x / (1.f + __expf(-x)); }

__global__ void k_poolkan(const unsigned short* __restrict__ hb2, const int* __restrict__ batch,
                          const float* __restrict__ bw1, const float* __restrict__ sw1,
                          const float* __restrict__ sc1, const float* __restrict__ bw2,
                          const float* __restrict__ sw2, const float* __restrict__ sc2,
                          float* __restrict__ out, int N) {
    __shared__ float sP[8][256];
    __shared__ float sB[D1][9];
    __shared__ float sS[D1];
    __shared__ float sZ[32];
    int g = blockIdx.x;
    int lo = 0, hi = N;
    while (lo < hi) { int m = (lo + hi) >> 1; if (batch[m] < g) lo = m + 1; else hi = m; }
    int lo2 = lo, hi2 = N;
    while (lo2 < hi2) { int m = (lo2 + hi2) >> 1; if (batch[m] < g + 1) lo2 = m + 1; else hi2 = m; }
    int i = threadIdx.x;
    int rg = i >> 5, cg = i & 31;
    float ps[8];
#pragma unroll
    for (int j = 0; j < 8; ++j) ps[j] = 0.f;
    const uint4* hv = (const uint4*)hb2;
    for (int n = lo + rg; n < lo2; n += 8) {
        uint4 u = hv[(size_t)n * 32 + cg];
        ps[0] += b2f_lo(u.x); ps[1] += b2f_hi(u.x);
        ps[2] += b2f_lo(u.y); ps[3] += b2f_hi(u.y);
        ps[4] += b2f_lo(u.z); ps[5] += b2f_hi(u.z);
        ps[6] += b2f_lo(u.w); ps[7] += b2f_hi(u.w);
    }
#pragma unroll
    for (int j = 0; j < 8; ++j) sP[rg][cg * 8 + j] = ps[j];
    __syncthreads();
    float xi = 0.f;
#pragma unroll
    for (int r2 = 0; r2 < 8; ++r2) xi += sP[r2][i];
    xi /= (float)max(lo2 - lo, 1);
    float b[8];
    bspl8(xi, b);
#pragma unroll
    for (int p = 0; p < 8; ++p) sB[i][p] = b[p];
    sS[i] = siluf(xi);
    __syncthreads();
    int wv = i >> 6, l = i & 63;
    for (int oo = 0; oo < 8; ++oo) {
        int o = wv * 8 + oo;
        float part = 0.f;
        for (int ii = l; ii < D1; ii += 64) {
            float sc = sc1[o * D1 + ii];
            float p0 = sS[ii] * bw1[o * D1 + ii];
            const float* sw = sw1 + ((size_t)o * D1 + ii) * 8;
#pragma unroll
            for (int p = 0; p < 8; ++p) p0 += sB[ii][p] * sw[p] * sc;
            part += p0;
        }
#pragma unroll
        for (int off = 32; off >= 1; off >>= 1) part += __shfl_down(part, off);
        if (l == 0) sZ[o] = part;
    }
    __syncthreads();
    if (i < 64) {
        float part = 0.f;
        if (i < 32) {
            float z = sZ[i];
            float b2a[8];
            bspl8(z, b2a);
            part = siluf(z) * bw2[i];
            float sc = sc2[i];
#pragma unroll
            for (int p = 0; p < 8; ++p) part += b2a[p] * sw2[i * 8 + p] * sc;
        }
#pragma unroll
        for (int off = 32; off >= 1; off >>= 1) part += __shfl_down(part, off);
        if (i == 0) out[g] = part;
    }
}

extern "C" void kernel_launch(void* const* d_in, const int* in_sizes, int n_in,
                              void* d_out, int out_size, void* d_ws, size_t ws_size,
                              hipStream_t stream) {
    const float* x      = (const float*)d_in[0];
    const int*   ei     = (const int*)d_in[1];
    const int*   batch  = (const int*)d_in[2];
    const float* W1     = (const float*)d_in[3];
    const float* asrc1  = (const float*)d_in[4];
    const float* adst1  = (const float*)d_in[5];
    const float* b1     = (const float*)d_in[6];
    const float* W2     = (const float*)d_in[7];
    const float* asrc2  = (const float*)d_in[8];
    const float* adst2  = (const float*)d_in[9];
    const float* b2     = (const float*)d_in[10];
    const float* bw1    = (const float*)d_in[11];
    const float* sw1    = (const float*)d_in[12];
    const float* sc1    = (const float*)d_in[13];
    const float* bw2    = (const float*)d_in[14];
    const float* sw2    = (const float*)d_in[15];
    const float* sc2    = (const float*)d_in[16];
    float* outp = (float*)d_out;

    const int N  = in_sizes[0] / 6;
    const int E  = in_sizes[1] / 2;
    const int ET = E + N;

    char* base = (char*)d_ws;
    unsigned short* hb  = (unsigned short*)base; base += (size_t)N * D1 * 2;
    unsigned short* xb  = (unsigned short*)base; base += (size_t)N * D1 * 2;
    unsigned short* hb2 = (unsigned short*)base; base += (size_t)N * D1 * 2;
    float* as_ = (float*)base;                   base += (size_t)N * HEADS * 4;
    float* ad_ = (float*)base;                   base += (size_t)N * HEADS * 4;
    float* xf8 = (float*)base;                   base += (size_t)N * 8 * 4;
    unsigned short* Btb = (unsigned short*)base; base += (size_t)264 * D1 * 2;
    float* va1 = (float*)base;                   base += 48 * 4;
    int* deg  = (int*)base;                      base += (size_t)N * 4;
    int* fill = (int*)base;                      base += (size_t)N * 4;
    int* rowp = (int*)base;                      base += (size_t)(N + 1) * 4;
    int* gcnt = (int*)base;                      base += 4;
    int* csrc = (int*)base;                      base += (size_t)ET * 4;

    const int TB = 256;
    int gN  = cdiv(N, TB);
    const int gXF = 2048;

    k_init<<<gN, TB, 0, stream>>>(W1, asrc1, adst1, W2, asrc2, adst2, Btb, va1, deg, fill, gcnt, N);
    k_dega<<<gXF, TB, 0, stream>>>(ei, E, ET, deg, x, va1, as_, ad_, xf8, N);
    k_off<<<gN, TB, 0, stream>>>(deg, rowp, gcnt, N);
    k_scatter<<<gXF, TB, 0, stream>>>(ei, E, ET, rowp, fill, csrc);
    k_aggr1<<<cdiv(N, 2), 128, 0, stream>>>(rowp, deg, csrc, as_, ad_, xf8, W1, b1, hb, N);
    k_mm<<<cdiv(N, 256) * 4, TB, 0, stream>>>(hb, Btb, xb, as_, ad_, N);
    k_aggr2<<<cdiv(N, 4), 128, 0, stream>>>(rowp, deg, csrc, as_, ad_, xb, b2, hb2, N);
    k_poolkan<<<NGR, TB, 0, stream>>>(hb2, batch, bw1, sw1, sc1, bw2, sw2, sc2, outp, N);
}